// Round 7
// baseline (168.656 us; speedup 1.0000x reference)
//
#include <hip/hip_runtime.h>

#define IMG_W 1024
#define IMG_H 1024

typedef float v4f __attribute__((ext_vector_type(4)));
typedef float v2f __attribute__((ext_vector_type(2)));

__global__ __launch_bounds__(256) void dir_rhs_kernel(
    const float* __restrict__ u,
    const float* __restrict__ f,
    const float* __restrict__ wt,
    float* __restrict__ out)
{
    // 16 images * 512 row-pairs = 8192 blocks.
    // XCD-chunked bijective swizzle (8192 % 8 == 0, 1024 tiles per XCD):
    // consecutive tiles on one XCD are consecutive row-pairs -> shared u rows
    // hit the same XCD's L2.
    const int orig = blockIdx.x;
    const int tile = (orig & 7) * 1024 + (orig >> 3);

    const int b   = tile >> 9;               // 512 row-pairs per image
    const int i0  = (tile & 511) << 1;       // output rows i0, i0+1
    const int tid = threadIdx.x;             // 0..255
    const int j0  = tid << 2;                // 4 columns per thread
    const size_t img = (size_t)b << 20;

    const float* ub = u + img;

    const bool le = (j0 == 0);               // thread covering col 0
    const bool re = (j0 == IMG_W - 4);       // thread covering col 1023

    // Clamped halo addresses, 8B-aligned float2 (coalesced; same line count
    // as the b128 version but half the VGPR cost).
    const int jl = le ? 0         : j0 - 2;  // .y = col j0-1
    const int jr = re ? IMG_W - 2 : j0 + 4;  // .x = col j0+4

    // ---- hoist ALL loads straight-line: 12 u loads + 2 f loads ----
    v4f c4[4]; v2f lv[4], rv[4]; float m[4];
    #pragma unroll
    for (int k = 0; k < 4; k++) {
        const int li = i0 - 1 + k;                                   // logical row
        const int rc = li < 0 ? 0 : (li > IMG_H - 1 ? IMG_H - 1 : li); // clamped
        const float* p = ub + (size_t)rc * IMG_W;
        c4[k] = *(const v4f*)(p + j0);
        lv[k] = *(const v2f*)(p + jl);
        rv[k] = *(const v2f*)(p + jr);
        m[k]  = (li >= 1 && li <= IMG_H - 2) ? 1.f : 0.f;  // row interior in v?
    }
    const float* fp = f + img + (size_t)i0 * IMG_W + j0;
    const v4f f0 = __builtin_nontemporal_load((const v4f*)fp);
    const v4f f1 = __builtin_nontemporal_load((const v4f*)(fp + IMG_W));

    // Broadcast weights (L1-cached)
    const float w00 = wt[0], w01 = wt[1], w02 = wt[2];
    const float w10 = wt[3], w11 = wt[4], w12 = wt[5];
    const float w20 = wt[6], w21 = wt[7], w22 = wt[8];
    const float cof = (float)(-(1.0 / 1023.0) * (1.0 / 1023.0) / 4.0);

    // Apply row-validity masks + Dirichlet column zeros.
    float lh[4], rh[4];
    #pragma unroll
    for (int k = 0; k < 4; k++) {
        lh[k] = le ? 0.f : lv[k].y * m[k];
        rh[k] = re ? 0.f : rv[k].x * m[k];
        c4[k] = c4[k] * m[k];
        if (le) c4[k].x = 0.f;               // col 0 boundary in v
        if (re) c4[k].w = 0.f;               // col 1023 boundary in v
    }

    const float keep0 = (i0 >= 1)         ? 1.f : 0.f;   // row i0 interior?
    const float keep1 = (i0 <= IMG_H - 3) ? 1.f : 0.f;   // row i0+1 interior?

    auto stencil = [&](int k, v4f fv, float keep) -> v4f {
        const v4f n = c4[k], cc = c4[k + 1], s = c4[k + 2];
        float r0 = cof * fv.x
                 + w00 * lh[k]     + w01 * n.x  + w02 * n.y
                 + w10 * lh[k + 1] + w11 * cc.x + w12 * cc.y
                 + w20 * lh[k + 2] + w21 * s.x  + w22 * s.y;
        float r1 = cof * fv.y
                 + w00 * n.x  + w01 * n.y  + w02 * n.z
                 + w10 * cc.x + w11 * cc.y + w12 * cc.z
                 + w20 * s.x  + w21 * s.y  + w22 * s.z;
        float r2 = cof * fv.z
                 + w00 * n.y  + w01 * n.z  + w02 * n.w
                 + w10 * cc.y + w11 * cc.z + w12 * cc.w
                 + w20 * s.y  + w21 * s.z  + w22 * s.w;
        float r3 = cof * fv.w
                 + w00 * n.z  + w01 * n.w  + w02 * rh[k]
                 + w10 * cc.z + w11 * cc.w + w12 * rh[k + 1]
                 + w20 * s.z  + w21 * s.w  + w22 * rh[k + 2];
        r0 *= keep; r1 *= keep; r2 *= keep; r3 *= keep;
        if (le) r0 = 0.f;                    // col 0 stays Dirichlet
        if (re) r3 = 0.f;                    // col 1023 stays Dirichlet
        return (v4f){r0, r1, r2, r3};
    };

    const v4f o0 = stencil(0, f0, keep0);
    const v4f o1 = stencil(1, f1, keep1);

    float* ob = out + img + (size_t)i0 * IMG_W + j0;
    __builtin_nontemporal_store(o0, (v4f*)ob);
    __builtin_nontemporal_store(o1, (v4f*)(ob + IMG_W));
}

extern "C" void kernel_launch(void* const* d_in, const int* in_sizes, int n_in,
                              void* d_out, int out_size, void* d_ws, size_t ws_size,
                              hipStream_t stream) {
    const float* u  = (const float*)d_in[0];
    const float* f  = (const float*)d_in[1];
    const float* wt = (const float*)d_in[2];
    float* out = (float*)d_out;

    const int B = 16;
    dim3 grid(B * (IMG_H / 2));   // one block per (batch, row-pair): 8192 blocks
    dim3 block(256);              // 256 threads * 4 cols = 1024-wide rows
    dir_rhs_kernel<<<grid, block, 0, stream>>>(u, f, wt, out);
}

// Round 8
// 167.772 us; speedup vs baseline: 1.0053x; 1.0053x over previous
//
#include <hip/hip_runtime.h>

#define IMG_W 1024
#define IMG_H 1024

typedef float v4f __attribute__((ext_vector_type(4)));

__global__ __launch_bounds__(256) void dir_rhs_kernel(
    const float* __restrict__ u,
    const float* __restrict__ f,
    const float* __restrict__ wt,
    float* __restrict__ out)
{
    // 16 images * 512 row-pairs = 8192 blocks, XCD-chunked bijective swizzle.
    const int orig = blockIdx.x;
    const int tile = (orig & 7) * 1024 + (orig >> 3);

    const int b    = tile >> 9;              // 512 row-pairs per image
    const int i0   = (tile & 511) << 1;      // output rows i0, i0+1
    const int tid  = threadIdx.x;            // 0..255
    const int wave = tid >> 6;               // 0..3
    const int lane = tid & 63;
    const int j0   = tid << 2;               // 4 columns per thread
    const size_t img = (size_t)b << 20;

    const float* ub = u + img;

    const bool le = (tid == 0);              // thread covering col 0
    const bool re = (tid == 255);            // thread covering col 1023

    // ---- ALL VMEM hoisted: 4 coalesced u-row loads + 2 NT f loads ----
    v4f c4[4]; float m[4];
    #pragma unroll
    for (int k = 0; k < 4; k++) {
        const int li = i0 - 1 + k;                                     // logical row
        const int rc = li < 0 ? 0 : (li > IMG_H - 1 ? IMG_H - 1 : li); // clamped
        c4[k] = *(const v4f*)(ub + (size_t)rc * IMG_W + j0);
        m[k]  = (li >= 1 && li <= IMG_H - 2) ? 1.f : 0.f;  // row interior in v?
    }
    const float* fp = f + img + (size_t)i0 * IMG_W + j0;
    const v4f f0 = __builtin_nontemporal_load((const v4f*)fp);
    const v4f f1 = __builtin_nontemporal_load((const v4f*)(fp + IMG_W));

    // Broadcast weights (L1-cached)
    const float w00 = wt[0], w01 = wt[1], w02 = wt[2];
    const float w10 = wt[3], w11 = wt[4], w12 = wt[5];
    const float w20 = wt[6], w21 = wt[7], w22 = wt[8];
    const float cof = (float)(-(1.0 / 1023.0) * (1.0 / 1023.0) / 4.0);

    // Row-validity masks + Dirichlet column zeros (before any exchange, so
    // every exchanged value is already a valid v-value).
    #pragma unroll
    for (int k = 0; k < 4; k++) {
        c4[k] = c4[k] * m[k];
        if (le) c4[k].x = 0.f;               // col 0 boundary in v
        if (re) c4[k].w = 0.f;               // col 1023 boundary in v
    }

    // ---- Column halos WITHOUT memory loads ----
    // Intra-wave: shuffle from the neighboring lane's registers.
    // Wave-boundary columns (cols 255/256, 511/512, 767/768): 128-B LDS exchange.
    __shared__ float ledge[4][4];            // [wave][k]: lane 0's  .x (span left edge)
    __shared__ float redge[4][4];            // [wave][k]: lane 63's .w (span right edge)
    if (lane == 0) {
        #pragma unroll
        for (int k = 0; k < 4; k++) ledge[wave][k] = c4[k].x;
    }
    if (lane == 63) {
        #pragma unroll
        for (int k = 0; k < 4; k++) redge[wave][k] = c4[k].w;
    }
    __syncthreads();

    float lh[4], rh[4];
    #pragma unroll
    for (int k = 0; k < 4; k++) {
        float l = __shfl_up(c4[k].w, 1);     // col j0-1 from lane-1
        float r = __shfl_down(c4[k].x, 1);   // col j0+4 from lane+1
        if (lane == 0)  l = (wave == 0) ? 0.f : redge[wave - 1][k];
        if (lane == 63) r = (wave == 3) ? 0.f : ledge[wave + 1][k];
        lh[k] = l; rh[k] = r;
    }

    const float keep0 = (i0 >= 1)         ? 1.f : 0.f;   // row i0 interior?
    const float keep1 = (i0 <= IMG_H - 3) ? 1.f : 0.f;   // row i0+1 interior?

    auto stencil = [&](int k, v4f fv, float keep) -> v4f {
        const v4f n = c4[k], cc = c4[k + 1], s = c4[k + 2];
        float r0 = cof * fv.x
                 + w00 * lh[k]     + w01 * n.x  + w02 * n.y
                 + w10 * lh[k + 1] + w11 * cc.x + w12 * cc.y
                 + w20 * lh[k + 2] + w21 * s.x  + w22 * s.y;
        float r1 = cof * fv.y
                 + w00 * n.x  + w01 * n.y  + w02 * n.z
                 + w10 * cc.x + w11 * cc.y + w12 * cc.z
                 + w20 * s.x  + w21 * s.y  + w22 * s.z;
        float r2 = cof * fv.z
                 + w00 * n.y  + w01 * n.z  + w02 * n.w
                 + w10 * cc.y + w11 * cc.z + w12 * cc.w
                 + w20 * s.y  + w21 * s.z  + w22 * s.w;
        float r3 = cof * fv.w
                 + w00 * n.z  + w01 * n.w  + w02 * rh[k]
                 + w10 * cc.z + w11 * cc.w + w12 * rh[k + 1]
                 + w20 * s.z  + w21 * s.w  + w22 * rh[k + 2];
        r0 *= keep; r1 *= keep; r2 *= keep; r3 *= keep;
        if (le) r0 = 0.f;                    // col 0 stays Dirichlet
        if (re) r3 = 0.f;                    // col 1023 stays Dirichlet
        return (v4f){r0, r1, r2, r3};
    };

    const v4f o0 = stencil(0, f0, keep0);
    const v4f o1 = stencil(1, f1, keep1);

    float* ob = out + img + (size_t)i0 * IMG_W + j0;
    __builtin_nontemporal_store(o0, (v4f*)ob);
    __builtin_nontemporal_store(o1, (v4f*)(ob + IMG_W));
}

extern "C" void kernel_launch(void* const* d_in, const int* in_sizes, int n_in,
                              void* d_out, int out_size, void* d_ws, size_t ws_size,
                              hipStream_t stream) {
    const float* u  = (const float*)d_in[0];
    const float* f  = (const float*)d_in[1];
    const float* wt = (const float*)d_in[2];
    float* out = (float*)d_out;

    const int B = 16;
    dim3 grid(B * (IMG_H / 2));   // one block per (batch, row-pair): 8192 blocks
    dim3 block(256);              // 256 threads * 4 cols = 1024-wide rows
    dir_rhs_kernel<<<grid, block, 0, stream>>>(u, f, wt, out);
}